// Round 9
// baseline (384.605 us; speedup 1.0000x reference)
//
#include <hip/hip_runtime.h>
#include <hip/hip_bf16.h>
#include <stdint.h>

// Problem constants
#define Hn 16
#define Tn 2048
#define En 1024
#define Dh 64

typedef __bf16 bf16x8 __attribute__((ext_vector_type(8)));
typedef float f32x4 __attribute__((ext_vector_type(4)));
typedef unsigned short u16;
typedef u16 u16x8 __attribute__((ext_vector_type(8)));

#define SCALE_Q 0.18033688f   // log2(e)/8 folded into Q at projection time

__device__ __forceinline__ u16 f2bf(float f) {
  union { float f; uint32_t u; } v; v.f = f;
  uint32_t r = v.u + 0x7fffu + ((v.u >> 16) & 1u);   // RNE
  return (u16)(r >> 16);
}

typedef const __attribute__((address_space(1))) void gvoid_t;
typedef __attribute__((address_space(3))) void lvoid_t;
__device__ __forceinline__ void gl_lds16(const void* g, void* l) {
  __builtin_amdgcn_global_load_lds((gvoid_t*)g, (lvoid_t*)l, 16, 0, 0);
}

// ---------------------------------------------------------------------------
// x (fp32) -> bf16. 8M elements, 4096 blocks x 256 thr x 8.
// ---------------------------------------------------------------------------
__global__ void cvt_x_k(const float* __restrict__ in, u16* __restrict__ out) {
  int i = (blockIdx.x * 256 + threadIdx.x) * 8;
  float4 a = *(const float4*)(in + i);
  float4 b = *(const float4*)(in + i + 4);
  u16x8 o;
  o[0] = f2bf(a.x); o[1] = f2bf(a.y); o[2] = f2bf(a.z); o[3] = f2bf(a.w);
  o[4] = f2bf(b.x); o[5] = f2bf(b.y); o[6] = f2bf(b.z); o[7] = f2bf(b.w);
  *(u16x8*)(out + i) = o;
}

// ---------------------------------------------------------------------------
// Weight transpose fp32 -> bf16: out[c*R + r] = bf16(in[r*C + c])
// ---------------------------------------------------------------------------
__global__ void transpose_cvt_k(const float* __restrict__ in, u16* __restrict__ out,
                                int R, int C) {
  __shared__ float tile[32][33];
  int c0 = blockIdx.x * 32, r0 = blockIdx.y * 32;
  for (int i = threadIdx.y; i < 32; i += 8)
    tile[i][threadIdx.x] = in[(size_t)(r0 + i) * C + c0 + threadIdx.x];
  __syncthreads();
  for (int i = threadIdx.y; i < 32; i += 8)
    out[(size_t)(c0 + i) * R + r0 + threadIdx.x] = f2bf(tile[threadIdx.x][i]);
}

// ---------------------------------------------------------------------------
// ids -> float key mask (0.0 keep / -1e30 pad); per-block int64 detection.
// ---------------------------------------------------------------------------
__global__ void prep_mask_k(const int* __restrict__ in, float* __restrict__ maskf) {
  __shared__ int is64_s;
  if (threadIdx.x == 0) {
    int all0 = 1;
    for (int i = 1; i < 256; i += 2) all0 &= (in[i] == 0);
    is64_s = all0;
  }
  __syncthreads();
  int i = blockIdx.x * 256 + threadIdx.x;
  int v = is64_s ? in[2 * i] : in[i];
  maskf[i] = (v != 0) ? 0.f : -1e30f;
}

// ---------------------------------------------------------------------------
// m97-style GEMM mainloop: C[128,128] += A[m0:.,:K] * Bt[n0:.,:K]^T  (bf16)
// ---------------------------------------------------------------------------
__device__ __forceinline__ void gemm_mainloop(const u16* __restrict__ A,
                                              const u16* __restrict__ Bt,
                                              int K, int m0, int n0,
                                              u16* lds, f32x4 acc[4][4]) {
  const int tid = threadIdx.x;
  const int lane = tid & 63;
  const int w = tid >> 6;
  const int wm = (w >> 1) * 64, wn = (w & 1) * 64;
  const int quad = lane >> 4, ln = lane & 15;

  const int e0 = w * 512 + lane * 8;      // wave-uniform base + lane*16B
  const int r0 = e0 >> 5, c0 = e0 & 31;

  const u16* gA0 = A + (size_t)(m0 + r0) * K + c0;
  const u16* gA1 = gA0 + (size_t)64 * K;
  const u16* gB0 = Bt + (size_t)(n0 + r0) * K + c0;
  const u16* gB1 = gB0 + (size_t)64 * K;
  u16* lA0 = lds + e0;
  u16* lA1 = lds + e0 + 2048;
  u16* lB0 = lds + e0 + 4096;
  u16* lB1 = lds + e0 + 6144;

  for (int k0 = 0; k0 < K; k0 += 32) {
    gl_lds16(gA0 + k0, lA0);
    gl_lds16(gA1 + k0, lA1);
    gl_lds16(gB0 + k0, lB0);
    gl_lds16(gB1 + k0, lB1);
    __syncthreads();
    bf16x8 af[4], bfr[4];
#pragma unroll
    for (int mt = 0; mt < 4; mt++)
      af[mt] = *(const bf16x8*)(lds + (wm + mt * 16 + ln) * 32 + quad * 8);
#pragma unroll
    for (int nt = 0; nt < 4; nt++)
      bfr[nt] = *(const bf16x8*)(lds + 4096 + (wn + nt * 16 + ln) * 32 + quad * 8);
#pragma unroll
    for (int mt = 0; mt < 4; mt++)
#pragma unroll
      for (int nt = 0; nt < 4; nt++)
        acc[mt][nt] = __builtin_amdgcn_mfma_f32_16x16x32_bf16(af[mt], bfr[nt],
                                                              acc[mt][nt], 0, 0, 0);
    __syncthreads();
  }
}

// ---------------------------------------------------------------------------
// GEMM 1: qkv = X @ Wqkv. Q (pre-scaled log2e/8) and K scatter directly;
// V-blocks stage the C-tile in LDS and write Vt[B,H,D,T] rows COALESCED
// (the old per-element scatter hit 64 cache lines per store instr).
// LDS: mainloop staging (first 8192 u16) is dead after the loop; Ct reuses it.
// Ct stride 130 u16 (dword-stride 65 == 1 mod 32): column reads conflict-free.
// ---------------------------------------------------------------------------
__global__ __launch_bounds__(256, 2)
void gemm_qkv_kernel(const u16* __restrict__ X, const u16* __restrict__ Wt,
                     u16* __restrict__ Qo, u16* __restrict__ Ko,
                     u16* __restrict__ Vto) {
  __shared__ __align__(16) u16 lds[128 * 130];
  const int m0 = blockIdx.y * 128, n0 = blockIdx.x * 128;
  f32x4 acc[4][4];
#pragma unroll
  for (int i = 0; i < 4; i++)
#pragma unroll
    for (int j = 0; j < 4; j++) acc[i][j] = (f32x4){0.f, 0.f, 0.f, 0.f};

  gemm_mainloop(X, Wt, En, m0, n0, lds, acc);

  const int tid = threadIdx.x, lane = tid & 63, w = tid >> 6;
  const int wm = (w >> 1) * 64, wn = (w & 1) * 64;
  const int quad = lane >> 4, ln = lane & 15;
  const int which = n0 >> 10;  // block-uniform: 0=Q 1=K 2=V
  const int bb = m0 >> 11, t0 = m0 & (Tn - 1);

  if (which < 2) {
#pragma unroll
    for (int mt = 0; mt < 4; mt++)
#pragma unroll
      for (int nt = 0; nt < 4; nt++)
#pragma unroll
        for (int r = 0; r < 4; r++) {
          int t = t0 + wm + mt * 16 + quad * 4 + r;   // C row = quad*4+reg
          int ng = n0 + wn + nt * 16 + ln;            // C col = lane&15
          int e = ng & (En - 1);
          int h = e >> 6, d = e & 63;
          size_t bh = (size_t)(bb * Hn + h);
          if (which == 0)
            Qo[(bh * Tn + t) * Dh + d] = f2bf(acc[mt][nt][r] * SCALE_Q);
          else
            Ko[(bh * Tn + t) * Dh + d] = f2bf(acc[mt][nt][r]);
        }
  } else {
    // stage C-tile -> LDS [128 rows(t)][130 stride, 128 cols(e)]
#pragma unroll
    for (int mt = 0; mt < 4; mt++)
#pragma unroll
      for (int nt = 0; nt < 4; nt++)
#pragma unroll
        for (int r = 0; r < 4; r++)
          lds[(wm + mt * 16 + quad * 4 + r) * 130 + wn + nt * 16 + ln] =
              f2bf(acc[mt][nt][r]);
    __syncthreads();
    const int ebase = n0 & (En - 1);
    // each wave writes 32 d-rows of Vt; lane covers t = lane and lane+64
#pragma unroll
    for (int i = 0; i < 32; i++) {
      int col = w * 32 + i;
      int e = ebase + col;
      int hh = e >> 6, d = e & 63;
      size_t vrow = (((size_t)(bb * Hn + hh)) * Dh + d) * Tn + t0;
      Vto[vrow + lane] = lds[lane * 130 + col];
      Vto[vrow + 64 + lane] = lds[(64 + lane) * 130 + col];
    }
  }
}

// ---------------------------------------------------------------------------
// GEMM 2: out = Y @ Wout + bias  -> fp32 output
// ---------------------------------------------------------------------------
__global__ __launch_bounds__(256, 2)
void gemm_out_kernel(const u16* __restrict__ Y, const u16* __restrict__ Wt,
                     const float* __restrict__ bias, float* __restrict__ Out) {
  __shared__ __align__(16) u16 lds[8192];
  const int m0 = blockIdx.y * 128, n0 = blockIdx.x * 128;
  f32x4 acc[4][4];
#pragma unroll
  for (int i = 0; i < 4; i++)
#pragma unroll
    for (int j = 0; j < 4; j++) acc[i][j] = (f32x4){0.f, 0.f, 0.f, 0.f};

  gemm_mainloop(Y, Wt, En, m0, n0, lds, acc);

  const int tid = threadIdx.x, lane = tid & 63, w = tid >> 6;
  const int wm = (w >> 1) * 64, wn = (w & 1) * 64;
  const int quad = lane >> 4, ln = lane & 15;

#pragma unroll
  for (int mt = 0; mt < 4; mt++)
#pragma unroll
    for (int nt = 0; nt < 4; nt++)
#pragma unroll
      for (int r = 0; r < 4; r++) {
        int mg = m0 + wm + mt * 16 + quad * 4 + r;
        int ng = n0 + wn + nt * 16 + ln;
        Out[(size_t)mg * En + ng] = acc[mt][nt][r] + bias[ng];
      }
}

// ---------------------------------------------------------------------------
// Flash attention: R6 block structure (4 waves share K/V tiles via L1)
// + R7 VALU diet. grid 1024 x 256 thr; block qt = 15-(bid>>6) (LPT),
// bh = bid&63 (XCD L2 affinity). Wave w owns q rows [qt*128+32w, +32).
// Barrier-free: K/V/Q fragments straight from global; only wave-private
// P rows round-trip LDS (stride 76, conflict-free). Pre-scaled Q -> exp2.
// Diagonal tile split out of the hot loop (wave-uniform phases).
// ---------------------------------------------------------------------------
__global__ __launch_bounds__(256, 4)
void attn_kernel(const u16* __restrict__ Q, const u16* __restrict__ K,
                 const u16* __restrict__ Vt, const float* __restrict__ maskf,
                 u16* __restrict__ Y) {
  __shared__ __align__(16) u16 Pl[128 * 76];

  const int bid = blockIdx.x;
  const int qt = 15 - (bid >> 6);     // LPT: heavy q-tiles first
  const int bh = bid & 63;
  const int b = bh >> 4, h = bh & 15;
  const int tid = threadIdx.x, lane = tid & 63, w = tid >> 6;
  const int quad = lane >> 4, ln = lane & 15;
  const int qb = w * 32;
  const int g0 = qt * 128 + qb;       // first q row of this wave

  const size_t baseQK = (size_t)bh * (Tn * Dh);
  const size_t baseV = (size_t)bh * (Dh * Tn);
  const float* mrow = maskf + b * Tn;

  // Q fragments (pre-scaled) in registers for the whole kernel
  bf16x8 aq[2][2];
#pragma unroll
  for (int rt = 0; rt < 2; rt++)
#pragma unroll
    for (int ks = 0; ks < 2; ks++)
      aq[rt][ks] = *(const bf16x8*)(Q + baseQK +
          (size_t)(g0 + rt * 16 + ln) * Dh + ks * 32 + quad * 8);

  f32x4 O[2][4];
  float lsum[2][4];
#pragma unroll
  for (int rt = 0; rt < 2; rt++) {
#pragma unroll
    for (int dt = 0; dt < 4; dt++) O[rt][dt] = (f32x4){0.f, 0.f, 0.f, 0.f};
#pragma unroll
    for (int r = 0; r < 4; r++) lsum[rt][r] = 0.f;
  }

  auto tile = [&](int k0, bool dg) {
    float kvf[4];
    bf16x8 bk[4][2], bv[4][2];
#pragma unroll
    for (int ct = 0; ct < 4; ct++) {
      kvf[ct] = mrow[k0 + ct * 16 + ln];
#pragma unroll
      for (int ks = 0; ks < 2; ks++)
        bk[ct][ks] = *(const bf16x8*)(K + baseQK +
            (size_t)(k0 + ct * 16 + ln) * Dh + ks * 32 + quad * 8);
    }
#pragma unroll
    for (int dt = 0; dt < 4; dt++)
#pragma unroll
      for (int ks = 0; ks < 2; ks++)
        bv[dt][ks] = *(const bf16x8*)(Vt + baseV +
            (size_t)(dt * 16 + ln) * Tn + k0 + ks * 32 + quad * 8);

#pragma unroll
    for (int rt = 0; rt < 2; rt++) {
      f32x4 s[4];
#pragma unroll
      for (int ct = 0; ct < 4; ct++) s[ct] = (f32x4){0.f, 0.f, 0.f, 0.f};
#pragma unroll
      for (int ks = 0; ks < 2; ks++)
#pragma unroll
        for (int ct = 0; ct < 4; ct++)
          s[ct] = __builtin_amdgcn_mfma_f32_16x16x32_bf16(aq[rt][ks], bk[ct][ks],
                                                          s[ct], 0, 0, 0);
      if (dg) {
#pragma unroll
        for (int ct = 0; ct < 4; ct++)
#pragma unroll
          for (int r = 0; r < 4; r++) {
            int qg = g0 + rt * 16 + quad * 4 + r;
            int kg = k0 + ct * 16 + ln;
            float v = (kg > qg) ? -1e30f : (s[ct][r] + kvf[ct]);
            float p = exp2f(fminf(v, 126.f));
            lsum[rt][r] += p;
            Pl[(qb + rt * 16 + quad * 4 + r) * 76 + ct * 16 + ln] = f2bf(p);
          }
      } else {
#pragma unroll
        for (int ct = 0; ct < 4; ct++)
#pragma unroll
          for (int r = 0; r < 4; r++) {
            float p = exp2f(fminf(s[ct][r] + kvf[ct], 126.f));
            lsum[rt][r] += p;
            Pl[(qb + rt * 16 + quad * 4 + r) * 76 + ct * 16 + ln] = f2bf(p);
          }
      }
    }

    // O += P V  (wave-local LDS round-trip; no barrier)
#pragma unroll
    for (int ks2 = 0; ks2 < 2; ks2++)
#pragma unroll
      for (int rt = 0; rt < 2; rt++) {
        bf16x8 ap = *(const bf16x8*)(Pl + (qb + rt * 16 + ln) * 76 + ks2 * 32 + quad * 8);
#pragma unroll
        for (int dt = 0; dt < 4; dt++)
          O[rt][dt] = __builtin_amdgcn_mfma_f32_16x16x32_bf16(ap, bv[dt][ks2],
                                                              O[rt][dt], 0, 0, 0);
      }
  };

  const int nfull = g0 >> 6;          // fully-unmasked key tiles
  for (int kt = 0; kt < nfull; kt++) tile(kt * 64, false);
  tile(nfull * 64, true);             // exactly one diagonal tile

  // epilogue: reduce lsum across the 16 lanes of each quad-row, write Y
#pragma unroll
  for (int rt = 0; rt < 2; rt++)
#pragma unroll
    for (int r = 0; r < 4; r++) {
      float l = lsum[rt][r];
#pragma unroll
      for (int off = 1; off < 16; off <<= 1) l += __shfl_xor(l, off);
      float inv = 1.f / l;
      int tg = g0 + rt * 16 + quad * 4 + r;
      size_t ob = ((size_t)b * Tn + tg) * En + h * Dh;
#pragma unroll
      for (int dt = 0; dt < 4; dt++)
        Y[ob + dt * 16 + ln] = f2bf(O[rt][dt][r] * inv);
    }
}

// ---------------------------------------------------------------------------
// Workspace (u16 units), ~58.8 MB. Vt scratch lives in d_out (dead before
// gemm_out overwrites it — stream-ordered).
// ---------------------------------------------------------------------------
#define OFF_MASK  0                       // 8192 floats = 16384 u16
#define OFF_WQKVT 16384
#define OFF_WOUTT (OFF_WQKVT + 3145728)
#define OFF_Q     (OFF_WOUTT + 1048576)
#define OFF_K     (OFF_Q + 8388608)
#define OFF_XY    (OFF_K + 8388608)

extern "C" void kernel_launch(void* const* d_in, const int* in_sizes, int n_in,
                              void* d_out, int out_size, void* d_ws, size_t ws_size,
                              hipStream_t stream) {
  const float* x = nullptr;      // 8388608
  const int* ids_raw = nullptr;  // 8192
  const float* wqkv = nullptr;   // 3145728
  const float* wout = nullptr;   // 1048576
  const float* bias = nullptr;   // 1024
  for (int i = 0; i < n_in; i++) {
    switch (in_sizes[i]) {
      case 8388608: x = (const float*)d_in[i]; break;
      case 8192:    ids_raw = (const int*)d_in[i]; break;
      case 3145728: wqkv = (const float*)d_in[i]; break;
      case 1048576: wout = (const float*)d_in[i]; break;
      case 1024:    bias = (const float*)d_in[i]; break;
      default: break;
    }
  }
  if (!x) x = (const float*)d_in[0];
  if (!ids_raw) ids_raw = (const int*)d_in[1];
  if (!wqkv) wqkv = (const float*)d_in[2];
  if (!wout) wout = (const float*)d_in[3];
  if (!bias) bias = (const float*)d_in[4];

  u16* ws = (u16*)d_ws;
  float* maskf = (float*)(ws + OFF_MASK);
  u16* wqkv_t = ws + OFF_WQKVT;
  u16* wout_t = ws + OFF_WOUTT;
  u16* Qb = ws + OFF_Q;
  u16* Kb = ws + OFF_K;
  u16* XbYb = ws + OFF_XY;      // Xb (bf16 x), later reused as Yb
  u16* Vtb = (u16*)d_out;       // V^T scratch inside fp32 d_out
  float* out = (float*)d_out;

  prep_mask_k<<<32, 256, 0, stream>>>(ids_raw, maskf);
  cvt_x_k<<<4096, 256, 0, stream>>>(x, XbYb);
  transpose_cvt_k<<<dim3(96, 32), dim3(32, 8), 0, stream>>>(wqkv, wqkv_t, 1024, 3072);
  transpose_cvt_k<<<dim3(32, 32), dim3(32, 8), 0, stream>>>(wout, wout_t, 1024, 1024);
  gemm_qkv_kernel<<<dim3(24, 64), 256, 0, stream>>>(XbYb, wqkv_t, Qb, Kb, Vtb);
  attn_kernel<<<1024, 256, 0, stream>>>(Qb, Kb, Vtb, maskf, XbYb);
  gemm_out_kernel<<<dim3(8, 64), 256, 0, stream>>>(XbYb, wout_t, bias, out);
}

// Round 10
// 333.497 us; speedup vs baseline: 1.1532x; 1.1532x over previous
//
#include <hip/hip_runtime.h>
#include <hip/hip_bf16.h>
#include <stdint.h>

// Problem constants
#define Hn 16
#define Tn 2048
#define En 1024
#define Dh 64

typedef __bf16 bf16x8 __attribute__((ext_vector_type(8)));
typedef float f32x4 __attribute__((ext_vector_type(4)));
typedef unsigned short u16;
typedef u16 u16x8 __attribute__((ext_vector_type(8)));

#define SCALE_Q 0.18033688f   // log2(e)/8 folded into Q at projection time

__device__ __forceinline__ u16 f2bf(float f) {
  union { float f; uint32_t u; } v; v.f = f;
  uint32_t r = v.u + 0x7fffu + ((v.u >> 16) & 1u);   // RNE
  return (u16)(r >> 16);
}

typedef const __attribute__((address_space(1))) void gvoid_t;
typedef __attribute__((address_space(3))) void lvoid_t;
__device__ __forceinline__ void gl_lds16(const void* g, void* l) {
  __builtin_amdgcn_global_load_lds((gvoid_t*)g, (lvoid_t*)l, 16, 0, 0);
}

// ---------------------------------------------------------------------------
// x (fp32) -> bf16. 8M elements, 4096 blocks x 256 thr x 8.
// ---------------------------------------------------------------------------
__global__ void cvt_x_k(const float* __restrict__ in, u16* __restrict__ out) {
  int i = (blockIdx.x * 256 + threadIdx.x) * 8;
  float4 a = *(const float4*)(in + i);
  float4 b = *(const float4*)(in + i + 4);
  u16x8 o;
  o[0] = f2bf(a.x); o[1] = f2bf(a.y); o[2] = f2bf(a.z); o[3] = f2bf(a.w);
  o[4] = f2bf(b.x); o[5] = f2bf(b.y); o[6] = f2bf(b.z); o[7] = f2bf(b.w);
  *(u16x8*)(out + i) = o;
}

// ---------------------------------------------------------------------------
// Weight transpose fp32 -> bf16: out[c*R + r] = bf16(in[r*C + c])
// ---------------------------------------------------------------------------
__global__ void transpose_cvt_k(const float* __restrict__ in, u16* __restrict__ out,
                                int R, int C) {
  __shared__ float tile[32][33];
  int c0 = blockIdx.x * 32, r0 = blockIdx.y * 32;
  for (int i = threadIdx.y; i < 32; i += 8)
    tile[i][threadIdx.x] = in[(size_t)(r0 + i) * C + c0 + threadIdx.x];
  __syncthreads();
  for (int i = threadIdx.y; i < 32; i += 8)
    out[(size_t)(c0 + i) * R + r0 + threadIdx.x] = f2bf(tile[threadIdx.x][i]);
}

// ---------------------------------------------------------------------------
// ids -> float key mask (0.0 keep / -1e30 pad); per-block int64 detection.
// ---------------------------------------------------------------------------
__global__ void prep_mask_k(const int* __restrict__ in, float* __restrict__ maskf) {
  __shared__ int is64_s;
  if (threadIdx.x == 0) {
    int all0 = 1;
    for (int i = 1; i < 256; i += 2) all0 &= (in[i] == 0);
    is64_s = all0;
  }
  __syncthreads();
  int i = blockIdx.x * 256 + threadIdx.x;
  int v = is64_s ? in[2 * i] : in[i];
  maskf[i] = (v != 0) ? 0.f : -1e30f;
}

// ---------------------------------------------------------------------------
// m97-style GEMM mainloop: C[128,128] += A[m0:.,:K] * Bt[n0:.,:K]^T  (bf16)
// ---------------------------------------------------------------------------
__device__ __forceinline__ void gemm_mainloop(const u16* __restrict__ A,
                                              const u16* __restrict__ Bt,
                                              int K, int m0, int n0,
                                              u16* lds, f32x4 acc[4][4]) {
  const int tid = threadIdx.x;
  const int lane = tid & 63;
  const int w = tid >> 6;
  const int wm = (w >> 1) * 64, wn = (w & 1) * 64;
  const int quad = lane >> 4, ln = lane & 15;

  const int e0 = w * 512 + lane * 8;      // wave-uniform base + lane*16B
  const int r0 = e0 >> 5, c0 = e0 & 31;

  const u16* gA0 = A + (size_t)(m0 + r0) * K + c0;
  const u16* gA1 = gA0 + (size_t)64 * K;
  const u16* gB0 = Bt + (size_t)(n0 + r0) * K + c0;
  const u16* gB1 = gB0 + (size_t)64 * K;
  u16* lA0 = lds + e0;
  u16* lA1 = lds + e0 + 2048;
  u16* lB0 = lds + e0 + 4096;
  u16* lB1 = lds + e0 + 6144;

  for (int k0 = 0; k0 < K; k0 += 32) {
    gl_lds16(gA0 + k0, lA0);
    gl_lds16(gA1 + k0, lA1);
    gl_lds16(gB0 + k0, lB0);
    gl_lds16(gB1 + k0, lB1);
    __syncthreads();
    bf16x8 af[4], bfr[4];
#pragma unroll
    for (int mt = 0; mt < 4; mt++)
      af[mt] = *(const bf16x8*)(lds + (wm + mt * 16 + ln) * 32 + quad * 8);
#pragma unroll
    for (int nt = 0; nt < 4; nt++)
      bfr[nt] = *(const bf16x8*)(lds + 4096 + (wn + nt * 16 + ln) * 32 + quad * 8);
#pragma unroll
    for (int mt = 0; mt < 4; mt++)
#pragma unroll
      for (int nt = 0; nt < 4; nt++)
        acc[mt][nt] = __builtin_amdgcn_mfma_f32_16x16x32_bf16(af[mt], bfr[nt],
                                                              acc[mt][nt], 0, 0, 0);
    __syncthreads();
  }
}

// ---------------------------------------------------------------------------
// GEMM 1: qkv = X @ Wqkv. Q (pre-scaled log2e/8) and K scatter directly;
// V-blocks stage the C-tile in LDS and write Vt[B,H,D,T] rows COALESCED.
// Ct stride 130 u16 (dword-stride 65 == 1 mod 32): column reads conflict-free.
// ---------------------------------------------------------------------------
__global__ __launch_bounds__(256, 2)
void gemm_qkv_kernel(const u16* __restrict__ X, const u16* __restrict__ Wt,
                     u16* __restrict__ Qo, u16* __restrict__ Ko,
                     u16* __restrict__ Vto) {
  __shared__ __align__(16) u16 lds[128 * 130];
  const int m0 = blockIdx.y * 128, n0 = blockIdx.x * 128;
  f32x4 acc[4][4];
#pragma unroll
  for (int i = 0; i < 4; i++)
#pragma unroll
    for (int j = 0; j < 4; j++) acc[i][j] = (f32x4){0.f, 0.f, 0.f, 0.f};

  gemm_mainloop(X, Wt, En, m0, n0, lds, acc);

  const int tid = threadIdx.x, lane = tid & 63, w = tid >> 6;
  const int wm = (w >> 1) * 64, wn = (w & 1) * 64;
  const int quad = lane >> 4, ln = lane & 15;
  const int which = n0 >> 10;  // block-uniform: 0=Q 1=K 2=V
  const int bb = m0 >> 11, t0 = m0 & (Tn - 1);

  if (which < 2) {
#pragma unroll
    for (int mt = 0; mt < 4; mt++)
#pragma unroll
      for (int nt = 0; nt < 4; nt++)
#pragma unroll
        for (int r = 0; r < 4; r++) {
          int t = t0 + wm + mt * 16 + quad * 4 + r;   // C row = quad*4+reg
          int ng = n0 + wn + nt * 16 + ln;            // C col = lane&15
          int e = ng & (En - 1);
          int h = e >> 6, d = e & 63;
          size_t bh = (size_t)(bb * Hn + h);
          if (which == 0)
            Qo[(bh * Tn + t) * Dh + d] = f2bf(acc[mt][nt][r] * SCALE_Q);
          else
            Ko[(bh * Tn + t) * Dh + d] = f2bf(acc[mt][nt][r]);
        }
  } else {
    // stage C-tile -> LDS [128 rows(t)][130 stride, 128 cols(e)]
#pragma unroll
    for (int mt = 0; mt < 4; mt++)
#pragma unroll
      for (int nt = 0; nt < 4; nt++)
#pragma unroll
        for (int r = 0; r < 4; r++)
          lds[(wm + mt * 16 + quad * 4 + r) * 130 + wn + nt * 16 + ln] =
              f2bf(acc[mt][nt][r]);
    __syncthreads();
    const int ebase = n0 & (En - 1);
    // each wave writes 32 d-rows of Vt; lane covers t = lane and lane+64
#pragma unroll
    for (int i = 0; i < 32; i++) {
      int col = w * 32 + i;
      int e = ebase + col;
      int hh = e >> 6, d = e & 63;
      size_t vrow = (((size_t)(bb * Hn + hh)) * Dh + d) * Tn + t0;
      Vto[vrow + lane] = lds[lane * 130 + col];
      Vto[vrow + 64 + lane] = lds[(64 + lane) * 130 + col];
    }
  }
}

// ---------------------------------------------------------------------------
// GEMM 2: out = Y @ Wout + bias  -> fp32 output
// ---------------------------------------------------------------------------
__global__ __launch_bounds__(256, 2)
void gemm_out_kernel(const u16* __restrict__ Y, const u16* __restrict__ Wt,
                     const float* __restrict__ bias, float* __restrict__ Out) {
  __shared__ __align__(16) u16 lds[8192];
  const int m0 = blockIdx.y * 128, n0 = blockIdx.x * 128;
  f32x4 acc[4][4];
#pragma unroll
  for (int i = 0; i < 4; i++)
#pragma unroll
    for (int j = 0; j < 4; j++) acc[i][j] = (f32x4){0.f, 0.f, 0.f, 0.f};

  gemm_mainloop(Y, Wt, En, m0, n0, lds, acc);

  const int tid = threadIdx.x, lane = tid & 63, w = tid >> 6;
  const int wm = (w >> 1) * 64, wn = (w & 1) * 64;
  const int quad = lane >> 4, ln = lane & 15;

#pragma unroll
  for (int mt = 0; mt < 4; mt++)
#pragma unroll
    for (int nt = 0; nt < 4; nt++)
#pragma unroll
      for (int r = 0; r < 4; r++) {
        int mg = m0 + wm + mt * 16 + quad * 4 + r;
        int ng = n0 + wn + nt * 16 + ln;
        Out[(size_t)mg * En + ng] = acc[mt][nt][r] + bias[ng];
      }
}

// ---------------------------------------------------------------------------
// Flash attention: 4 waves share K/V tiles via L1; launch_bounds (256,3)
// (R9's (256,4) squeezed VGPR 84->64 -> scratch spills, WRITE 16->62MB).
// bk/bv live ranges split: K frags -> QK MFMA -> V frags -> exp -> PV.
// Barrier-free; P round-trip in LDS stride 76; pre-scaled Q -> exp2.
// ---------------------------------------------------------------------------
__global__ __launch_bounds__(256, 3)
void attn_kernel(const u16* __restrict__ Q, const u16* __restrict__ K,
                 const u16* __restrict__ Vt, const float* __restrict__ maskf,
                 u16* __restrict__ Y) {
  __shared__ __align__(16) u16 Pl[128 * 76];

  const int bid = blockIdx.x;
  const int qt = 15 - (bid >> 6);     // LPT: heavy q-tiles first
  const int bh = bid & 63;
  const int b = bh >> 4, h = bh & 15;
  const int tid = threadIdx.x, lane = tid & 63, w = tid >> 6;
  const int quad = lane >> 4, ln = lane & 15;
  const int qb = w * 32;
  const int g0 = qt * 128 + qb;       // first q row of this wave

  const size_t baseQK = (size_t)bh * (Tn * Dh);
  const size_t baseV = (size_t)bh * (Dh * Tn);
  const float* mrow = maskf + b * Tn;

  // Q fragments (pre-scaled) in registers for the whole kernel
  bf16x8 aq[2][2];
#pragma unroll
  for (int rt = 0; rt < 2; rt++)
#pragma unroll
    for (int ks = 0; ks < 2; ks++)
      aq[rt][ks] = *(const bf16x8*)(Q + baseQK +
          (size_t)(g0 + rt * 16 + ln) * Dh + ks * 32 + quad * 8);

  f32x4 O[2][4];
  float lsum[2][4];
#pragma unroll
  for (int rt = 0; rt < 2; rt++) {
#pragma unroll
    for (int dt = 0; dt < 4; dt++) O[rt][dt] = (f32x4){0.f, 0.f, 0.f, 0.f};
#pragma unroll
    for (int r = 0; r < 4; r++) lsum[rt][r] = 0.f;
  }

  auto tile = [&](int k0, bool dg) {
    // ---- phase 1: K fragments + QK^T ----
    float kvf[4];
    f32x4 s[2][4];
    {
      bf16x8 bk[4][2];
#pragma unroll
      for (int ct = 0; ct < 4; ct++) {
        kvf[ct] = mrow[k0 + ct * 16 + ln];
#pragma unroll
        for (int ks = 0; ks < 2; ks++)
          bk[ct][ks] = *(const bf16x8*)(K + baseQK +
              (size_t)(k0 + ct * 16 + ln) * Dh + ks * 32 + quad * 8);
      }
#pragma unroll
      for (int rt = 0; rt < 2; rt++)
#pragma unroll
        for (int ct = 0; ct < 4; ct++)
          s[rt][ct] = (f32x4){0.f, 0.f, 0.f, 0.f};
#pragma unroll
      for (int ks = 0; ks < 2; ks++)
#pragma unroll
        for (int rt = 0; rt < 2; rt++)
#pragma unroll
          for (int ct = 0; ct < 4; ct++)
            s[rt][ct] = __builtin_amdgcn_mfma_f32_16x16x32_bf16(aq[rt][ks], bk[ct][ks],
                                                                s[rt][ct], 0, 0, 0);
    }  // bk dead here

    // ---- phase 2: V fragments issued, latency hidden behind exp ----
    bf16x8 bv[4][2];
#pragma unroll
    for (int dt = 0; dt < 4; dt++)
#pragma unroll
      for (int ks = 0; ks < 2; ks++)
        bv[dt][ks] = *(const bf16x8*)(Vt + baseV +
            (size_t)(dt * 16 + ln) * Tn + k0 + ks * 32 + quad * 8);

#pragma unroll
    for (int rt = 0; rt < 2; rt++) {
      if (dg) {
#pragma unroll
        for (int ct = 0; ct < 4; ct++)
#pragma unroll
          for (int r = 0; r < 4; r++) {
            int qg = g0 + rt * 16 + quad * 4 + r;
            int kg = k0 + ct * 16 + ln;
            float v = (kg > qg) ? -1e30f : (s[rt][ct][r] + kvf[ct]);
            float p = exp2f(fminf(v, 126.f));
            lsum[rt][r] += p;
            Pl[(qb + rt * 16 + quad * 4 + r) * 76 + ct * 16 + ln] = f2bf(p);
          }
      } else {
#pragma unroll
        for (int ct = 0; ct < 4; ct++)
#pragma unroll
          for (int r = 0; r < 4; r++) {
            float p = exp2f(fminf(s[rt][ct][r] + kvf[ct], 126.f));
            lsum[rt][r] += p;
            Pl[(qb + rt * 16 + quad * 4 + r) * 76 + ct * 16 + ln] = f2bf(p);
          }
      }
    }

    // ---- phase 3: O += P V (wave-local LDS round-trip; no barrier) ----
#pragma unroll
    for (int ks2 = 0; ks2 < 2; ks2++)
#pragma unroll
      for (int rt = 0; rt < 2; rt++) {
        bf16x8 ap = *(const bf16x8*)(Pl + (qb + rt * 16 + ln) * 76 + ks2 * 32 + quad * 8);
#pragma unroll
        for (int dt = 0; dt < 4; dt++)
          O[rt][dt] = __builtin_amdgcn_mfma_f32_16x16x32_bf16(ap, bv[dt][ks2],
                                                              O[rt][dt], 0, 0, 0);
      }
  };

  const int nfull = g0 >> 6;          // fully-unmasked key tiles
  for (int kt = 0; kt < nfull; kt++) tile(kt * 64, false);
  tile(nfull * 64, true);             // exactly one diagonal tile

  // epilogue: reduce lsum across the 16 lanes of each quad-row, write Y
#pragma unroll
  for (int rt = 0; rt < 2; rt++)
#pragma unroll
    for (int r = 0; r < 4; r++) {
      float l = lsum[rt][r];
#pragma unroll
      for (int off = 1; off < 16; off <<= 1) l += __shfl_xor(l, off);
      float inv = 1.f / l;
      int tg = g0 + rt * 16 + quad * 4 + r;
      size_t ob = ((size_t)b * Tn + tg) * En + h * Dh;
#pragma unroll
      for (int dt = 0; dt < 4; dt++)
        Y[ob + dt * 16 + ln] = f2bf(O[rt][dt][r] * inv);
    }
}

// ---------------------------------------------------------------------------
// Workspace (u16 units), ~58.8 MB. Vt scratch lives in d_out (dead before
// gemm_out overwrites it — stream-ordered).
// ---------------------------------------------------------------------------
#define OFF_MASK  0                       // 8192 floats = 16384 u16
#define OFF_WQKVT 16384
#define OFF_WOUTT (OFF_WQKVT + 3145728)
#define OFF_Q     (OFF_WOUTT + 1048576)
#define OFF_K     (OFF_Q + 8388608)
#define OFF_XY    (OFF_K + 8388608)

extern "C" void kernel_launch(void* const* d_in, const int* in_sizes, int n_in,
                              void* d_out, int out_size, void* d_ws, size_t ws_size,
                              hipStream_t stream) {
  const float* x = nullptr;      // 8388608
  const int* ids_raw = nullptr;  // 8192
  const float* wqkv = nullptr;   // 3145728
  const float* wout = nullptr;   // 1048576
  const float* bias = nullptr;   // 1024
  for (int i = 0; i < n_in; i++) {
    switch (in_sizes[i]) {
      case 8388608: x = (const float*)d_in[i]; break;
      case 8192:    ids_raw = (const int*)d_in[i]; break;
      case 3145728: wqkv = (const float*)d_in[i]; break;
      case 1048576: wout = (const float*)d_in[i]; break;
      case 1024:    bias = (const float*)d_in[i]; break;
      default: break;
    }
  }
  if (!x) x = (const float*)d_in[0];
  if (!ids_raw) ids_raw = (const int*)d_in[1];
  if (!wqkv) wqkv = (const float*)d_in[2];
  if (!wout) wout = (const float*)d_in[3];
  if (!bias) bias = (const float*)d_in[4];

  u16* ws = (u16*)d_ws;
  float* maskf = (float*)(ws + OFF_MASK);
  u16* wqkv_t = ws + OFF_WQKVT;
  u16* wout_t = ws + OFF_WOUTT;
  u16* Qb = ws + OFF_Q;
  u16* Kb = ws + OFF_K;
  u16* XbYb = ws + OFF_XY;      // Xb (bf16 x), later reused as Yb
  u16* Vtb = (u16*)d_out;       // V^T scratch inside fp32 d_out
  float* out = (float*)d_out;

  prep_mask_k<<<32, 256, 0, stream>>>(ids_raw, maskf);
  cvt_x_k<<<4096, 256, 0, stream>>>(x, XbYb);
  transpose_cvt_k<<<dim3(96, 32), dim3(32, 8), 0, stream>>>(wqkv, wqkv_t, 1024, 3072);
  transpose_cvt_k<<<dim3(32, 32), dim3(32, 8), 0, stream>>>(wout, wout_t, 1024, 1024);
  gemm_qkv_kernel<<<dim3(24, 64), 256, 0, stream>>>(XbYb, wqkv_t, Qb, Kb, Vtb);
  attn_kernel<<<1024, 256, 0, stream>>>(Qb, Kb, Vtb, maskf, XbYb);
  gemm_out_kernel<<<dim3(8, 64), 256, 0, stream>>>(XbYb, wout_t, bias, out);
}